// Round 9
// baseline (204.206 us; speedup 1.0000x reference)
//
#include <hip/hip_runtime.h>

typedef _Float16 half8 __attribute__((ext_vector_type(8)));
typedef _Float16 half4 __attribute__((ext_vector_type(4)));
typedef float f32x4 __attribute__((ext_vector_type(4)));

#define ATT_SCALE 0.03125f   // 1/sqrt(1024)
#define S_LEN 2048
#define D_DIM 1024
#define NB 4

// async 16B HBM -> LDS copy (gfx950 global_load_lds_dwordx4).
// LDS dest must be wave-uniform base; HW adds lane*16.
__device__ __forceinline__ void async_cp16(const _Float16* g, _Float16* l)
{
    __builtin_amdgcn_global_load_lds(
        (const __attribute__((address_space(1))) void*)g,
        (__attribute__((address_space(3))) void*)l, 16, 0, 0);
}

// ---------------------------------------------------------------------------
// Shared GEMM core, BK=64 m97-structure (round-8 verified: 0 bank conflicts,
// multi-block overlap). Used by scores_exp / pv.
// ---------------------------------------------------------------------------
__device__ __forceinline__ void gemm_core64(const _Float16* __restrict__ Ag,
                                            const _Float16* __restrict__ Bg,
                                            int lda, int ldb, int ksteps64,
                                            f32x4 acc[4][4])
{
    __shared__ _Float16 As[128 * 64];
    __shared__ _Float16 Bs[128 * 64];

    const int t    = threadIdx.x;
    const int wave = t >> 6;
    const int lane = t & 63;
    const int wm   = (wave >> 1) * 64;
    const int wn   = (wave & 1) * 64;
    const int lg   = lane >> 4;
    const int lr   = lane & 15;

    const int tr = t >> 3;
    const int tc = ((t & 7) ^ (tr & 7)) * 8;       // swizzled source col (halves)
    const int ldso = wave * 512;

    const _Float16* ap0 = Ag + (long)(0 * 32 + tr) * lda + tc;
    const _Float16* ap1 = Ag + (long)(1 * 32 + tr) * lda + tc;
    const _Float16* ap2 = Ag + (long)(2 * 32 + tr) * lda + tc;
    const _Float16* ap3 = Ag + (long)(3 * 32 + tr) * lda + tc;
    const _Float16* bp0 = Bg + (long)(0 * 32 + tr) * ldb + tc;
    const _Float16* bp1 = Bg + (long)(1 * 32 + tr) * ldb + tc;
    const _Float16* bp2 = Bg + (long)(2 * 32 + tr) * ldb + tc;
    const _Float16* bp3 = Bg + (long)(3 * 32 + tr) * ldb + tc;

    const int arow = wm + lr;
    const int brow = wn + lr;

    for (int ks = 0; ks < ksteps64; ++ks) {
        __syncthreads();
        async_cp16(ap0, As + 0 * 2048 + ldso);
        async_cp16(ap1, As + 1 * 2048 + ldso);
        async_cp16(ap2, As + 2 * 2048 + ldso);
        async_cp16(ap3, As + 3 * 2048 + ldso);
        async_cp16(bp0, Bs + 0 * 2048 + ldso);
        async_cp16(bp1, Bs + 1 * 2048 + ldso);
        async_cp16(bp2, Bs + 2 * 2048 + ldso);
        async_cp16(bp3, Bs + 3 * 2048 + ldso);
        __syncthreads();

        ap0 += 64; ap1 += 64; ap2 += 64; ap3 += 64;
        bp0 += 64; bp1 += 64; bp2 += 64; bp3 += 64;

#pragma unroll
        for (int kk = 0; kk < 2; ++kk) {
            half8 af[4], bf[4];
#pragma unroll
            for (int mf = 0; mf < 4; ++mf) {
                const int row = arow + mf * 16;
                const int hof = (kk * 32 + lg * 8) ^ ((row & 7) * 8);
                af[mf] = *(const half8*)&As[row * 64 + hof];
            }
#pragma unroll
            for (int nf = 0; nf < 4; ++nf) {
                const int row = brow + nf * 16;
                const int hof = (kk * 32 + lg * 8) ^ ((row & 7) * 8);
                bf[nf] = *(const half8*)&Bs[row * 64 + hof];
            }
#pragma unroll
            for (int mf = 0; mf < 4; ++mf)
#pragma unroll
                for (int nf = 0; nf < 4; ++nf)
                    acc[mf][nf] = __builtin_amdgcn_mfma_f32_16x16x32_f16(
                        af[mf], bf[nf], acc[mf][nf], 0, 0, 0);
        }
    }
}

// ---------------------------------------------------------------------------
// 0) fused init: cast x fp32->fp16, zero out, zero row sums, AND
//    transpose+cast W (blocks >= 8192). One launch, 256-thr blocks.
// ---------------------------------------------------------------------------
__global__ void init_kernel(const float* __restrict__ X, _Float16* __restrict__ Xh,
                            float4* __restrict__ out, float* __restrict__ rs,
                            const float* __restrict__ Wq, const float* __restrict__ Wk,
                            const float* __restrict__ Wv, _Float16* __restrict__ Wt)
{
    const int bid = blockIdx.x;
    const int t   = threadIdx.x;
    if (bid < 8192) {
        const int i = bid * 256 + t;                 // 0 .. 2097151
        float4 v = ((const float4*)X)[i];
        half4 h;
        h.x = (_Float16)v.x; h.y = (_Float16)v.y; h.z = (_Float16)v.z; h.w = (_Float16)v.w;
        ((half4*)Xh)[i] = h;
        out[i] = (float4){0.f, 0.f, 0.f, 0.f};
        if (i < NB * S_LEN) rs[i] = 0.f;
        return;
    }
    // W transpose: 3072 blocks: w = bb/1024, tile (n0,k0) 32x32
    __shared__ float tile[32][33];
    const int bb = bid - 8192;
    const int w  = bb >> 10;
    const int rem = bb & 1023;
    const int n0 = (rem & 31) * 32, k0 = (rem >> 5) * 32;
    const float* Wsrc = (w == 0) ? Wq : (w == 1) ? Wk : Wv;
    _Float16* dst = Wt + (long)w * D_DIM * D_DIM;
    const int tx = t & 31, ty = t >> 5;
#pragma unroll
    for (int j = 0; j < 4; ++j)
        tile[ty + 8 * j][tx] = Wsrc[(long)(k0 + ty + 8 * j) * D_DIM + n0 + tx];
    __syncthreads();
#pragma unroll
    for (int j = 0; j < 4; ++j)
        dst[(long)(n0 + ty + 8 * j) * D_DIM + k0 + tx] = (_Float16)tile[tx][ty + 8 * j];
}

// ---------------------------------------------------------------------------
// 3) FUSED QKV projection: one block computes the (mt,nt) 128x128 tile of
//    Q, K AND V — A-tile staged once, 3 B-tiles, 48 MFMA/wave per K-step
//    (3x the MFMA per barrier event of the unfused core at the same 8
//    gload_lds/step). BK=32; LDS = A 8KB + 3xB 8KB = 32 KB.
//    acc[3][4][4] = 192 VGPR (static indexing only). Grid 512 = 2 exact
//    rounds; XCD-chunked so 8 consecutive blocks share (mt-group, all nt).
//    Swizzle (BK=32 contraction of the round-8-verified form): granule
//    (16B) index ^= row&3, applied on global source and ds_read (rule 21).
// ---------------------------------------------------------------------------
__global__ __launch_bounds__(256) void proj_kernel(const _Float16* __restrict__ Xh,
                                                   const _Float16* __restrict__ Wt,
                                                   _Float16* __restrict__ Q,
                                                   _Float16* __restrict__ K,
                                                   _Float16* __restrict__ V)
{
    __shared__ _Float16 As[128 * 32];
    __shared__ _Float16 Bs[3][128 * 32];

    const int bid = blockIdx.x;                  // 0..511
    const int g   = (bid & 7) * 64 + (bid >> 3); // bijective XCD chunking
    const int mt  = g >> 3;                      // 0..63
    const int nt  = g & 7;                       // 0..7

    const int t    = threadIdx.x;
    const int wave = t >> 6;
    const int lane = t & 63;
    const int wm   = (wave >> 1) * 64;
    const int wn   = (wave & 1) * 64;
    const int lg   = lane >> 4;
    const int lr   = lane & 15;

    // staging: per matrix 2 instrs (seg 0/1 = rows 0-63/64-127); thread t
    // covers row seg*64 + (t>>2), source granule (t&3)^(row&3); linear LDS.
    const int sr  = t >> 2;
    const int scg = ((t & 3) ^ (sr & 3)) * 8;    // halves
    const int ldso = wave * 512;                 // halves (+ seg*2048)

    const _Float16* a0 = Xh + ((long)mt * 128 + sr) * D_DIM + scg;
    const _Float16* a1 = a0 + 64 * D_DIM;
    const _Float16* b0[3], * b1[3];
#pragma unroll
    for (int w = 0; w < 3; ++w) {
        b0[w] = Wt + (long)w * D_DIM * D_DIM + ((long)nt * 128 + sr) * D_DIM + scg;
        b1[w] = b0[w] + 64 * D_DIM;
    }

    f32x4 acc[3][4][4];
#pragma unroll
    for (int w = 0; w < 3; ++w)
#pragma unroll
        for (int i = 0; i < 4; ++i)
#pragma unroll
            for (int j = 0; j < 4; ++j) acc[w][i][j] = (f32x4){0.f, 0.f, 0.f, 0.f};

    const int arow = wm + lr;
    const int brow = wn + lr;
    const int hswz = lg ^ (lr & 3);              // granule after swizzle

    for (int ks = 0; ks < 32; ++ks) {
        __syncthreads();
        async_cp16(a0, As + 0 * 2048 + ldso);
        async_cp16(a1, As + 1 * 2048 + ldso);
#pragma unroll
        for (int w = 0; w < 3; ++w) {
            async_cp16(b0[w], Bs[w] + 0 * 2048 + ldso);
            async_cp16(b1[w], Bs[w] + 1 * 2048 + ldso);
        }
        __syncthreads();

        a0 += 32; a1 += 32;
#pragma unroll
        for (int w = 0; w < 3; ++w) { b0[w] += 32; b1[w] += 32; }

        half8 af[4];
#pragma unroll
        for (int mf = 0; mf < 4; ++mf)
            af[mf] = *(const half8*)&As[(arow + mf * 16) * 32 + hswz * 8];

#pragma unroll
        for (int w = 0; w < 3; ++w) {
            half8 bf[4];
#pragma unroll
            for (int nf = 0; nf < 4; ++nf)
                bf[nf] = *(const half8*)&Bs[w][(brow + nf * 16) * 32 + hswz * 8];
#pragma unroll
            for (int mf = 0; mf < 4; ++mf)
#pragma unroll
                for (int nf = 0; nf < 4; ++nf)
                    acc[w][mf][nf] = __builtin_amdgcn_mfma_f32_16x16x32_f16(
                        af[mf], bf[nf], acc[w][mf][nf], 0, 0, 0);
        }
    }

    const long row0 = (long)mt * 128 + wm + 4 * lg;
    const long col0 = (long)nt * 128 + wn + lr;
#pragma unroll
    for (int w = 0; w < 3; ++w) {
        _Float16* C = (w == 0) ? Q : (w == 1) ? K : V;
#pragma unroll
        for (int i = 0; i < 4; ++i)
#pragma unroll
            for (int j = 0; j < 4; ++j)
#pragma unroll
                for (int r = 0; r < 4; ++r)
                    C[(row0 + i * 16 + r) * D_DIM + col0 + j * 16] = (_Float16)acc[w][i][j][r];
    }
}

// ---------------------------------------------------------------------------
// 4) transpose V [b][s][d] -> Vt [b][d][s] (fp16), half8 both ways.
// ---------------------------------------------------------------------------
__global__ __launch_bounds__(256) void transpose_v_kernel(const _Float16* __restrict__ V,
                                                          _Float16* __restrict__ Vt)
{
    __shared__ _Float16 tile[64][72];
    const int d0 = blockIdx.x * 64, s0 = blockIdx.y * 64;
    const long b = blockIdx.z;
    const _Float16* Vb = V + b * S_LEN * D_DIM;
    _Float16* Vtb = Vt + b * D_DIM * S_LEN;
    const int t = threadIdx.x;
    const int sr = t >> 3, c8 = (t & 7) * 8;

    *(half8*)&tile[sr][c8]      = *(const half8*)&Vb[(long)(s0 + sr) * D_DIM + d0 + c8];
    *(half8*)&tile[sr + 32][c8] = *(const half8*)&Vb[(long)(s0 + sr + 32) * D_DIM + d0 + c8];
    __syncthreads();

    const int dr = t >> 3, s8 = (t & 7) * 8;
    half8 o0, o1;
#pragma unroll
    for (int e = 0; e < 8; ++e) {
        o0[e] = tile[s8 + e][dr];
        o1[e] = tile[s8 + e][dr + 32];
    }
    *(half8*)&Vtb[(long)(d0 + dr) * S_LEN + s0 + s8]      = o0;
    *(half8*)&Vtb[(long)(d0 + dr + 32) * S_LEN + s0 + s8] = o1;
}

// ---------------------------------------------------------------------------
// 5) fused scores+exp: P = exp(scale*QK^T) (causal, UNNORMALIZED, fp16),
//    row sums via atomicAdd. Triangular 544-block grid, XCD-balanced.
// ---------------------------------------------------------------------------
__global__ __launch_bounds__(256) void scores_exp_kernel(const _Float16* __restrict__ Q,
                                                         const _Float16* __restrict__ K,
                                                         _Float16* __restrict__ P,
                                                         float* __restrict__ row_sum)
{
    const int xcd = blockIdx.x & 7;
    const int idx = blockIdx.x >> 3;      // 0..67
    const int b   = idx / 17;
    const int l   = idx % 17;
    int qt, kt;
    if (l <= xcd) { qt = xcd;      kt = l; }
    else          { qt = 15 - xcd; kt = l - xcd - 1; }

    f32x4 acc[4][4];
#pragma unroll
    for (int i = 0; i < 4; ++i)
#pragma unroll
        for (int j = 0; j < 4; ++j) acc[i][j] = (f32x4){0.f, 0.f, 0.f, 0.f};

    const _Float16* Ag = Q + ((long)b * S_LEN + qt * 128) * D_DIM;
    const _Float16* Bg = K + ((long)b * S_LEN + kt * 128) * D_DIM;
    gemm_core64(Ag, Bg, D_DIM, D_DIM, D_DIM / 64, acc);

    _Float16* Pb = P + (long)b * S_LEN * S_LEN;
    float* rsb = row_sum + (long)b * S_LEN;
    const int t = threadIdx.x, wave = t >> 6, lane = t & 63;
    const int wm = (wave >> 1) * 64, wn = (wave & 1) * 64;
    const int lg = lane >> 4, lr = lane & 15;
    const int row0 = qt * 128 + wm + 4 * lg;
    const int col0 = kt * 128 + wn + lr;

#pragma unroll
    for (int i = 0; i < 4; ++i) {
#pragma unroll
        for (int r = 0; r < 4; ++r) {
            const int row = row0 + i * 16 + r;
            float s = 0.f;
#pragma unroll
            for (int j = 0; j < 4; ++j) {
                const int col = col0 + j * 16;
                float p = (col <= row) ? __expf(acc[i][j][r] * ATT_SCALE) : 0.f;
                s += p;
                Pb[(long)row * S_LEN + col] = (_Float16)p;
            }
#pragma unroll
            for (int off = 1; off < 16; off <<= 1) s += __shfl_xor(s, off, 64);
            if (lr == 0) atomicAdd(&rsb[row], s);
        }
    }
}

// ---------------------------------------------------------------------------
// 6) O = (P @ V) / row_sum, split-K + XCD balance (BK=64).
// ---------------------------------------------------------------------------
__global__ __launch_bounds__(256) void pv_kernel(const _Float16* __restrict__ P,
                                                 const _Float16* __restrict__ Vt,
                                                 const float* __restrict__ row_sum,
                                                 float* __restrict__ O)
{
    const int xcd = blockIdx.x & 7;
    int r = blockIdx.x >> 3;              // 0..95
    const int b = r / 24;  r %= 24;
    const int j = r >> 3;
    const int nt = r & 7;
    const int sl = (j == 0) ? (7 - xcd) : (j == 1 ? 8 + 2 * xcd : 9 + 2 * xcd);

    int qt, k0, ks64;
    if (sl < 8) { qt = sl; k0 = 0; ks64 = (qt + 1) * 2; }
    else {
        const int e = sl - 8;
        qt = 8 + (e >> 1);
        ks64 = qt + 1;
        k0 = (e & 1) * ks64 * 64;
    }

    f32x4 acc[4][4];
#pragma unroll
    for (int i = 0; i < 4; ++i)
#pragma unroll
        for (int jj = 0; jj < 4; ++jj) acc[i][jj] = (f32x4){0.f, 0.f, 0.f, 0.f};

    const _Float16* Ag = P + ((long)b * S_LEN + qt * 128) * S_LEN + k0;
    const _Float16* Bg = Vt + (long)b * D_DIM * S_LEN + (long)nt * 128 * S_LEN + k0;
    gemm_core64(Ag, Bg, S_LEN, S_LEN, ks64, acc);

    float* Ob = O + (long)b * S_LEN * D_DIM;
    const float* rsb = row_sum + (long)b * S_LEN;
    const int t = threadIdx.x, wave = t >> 6, lane = t & 63;
    const int wm = (wave >> 1) * 64, wn = (wave & 1) * 64;
    const int lg = lane >> 4, lr = lane & 15;
    const long row0 = qt * 128 + wm + 4 * lg;
    const long col0 = (long)nt * 128 + wn + lr;

    if (sl < 8) {
#pragma unroll
        for (int i = 0; i < 4; ++i)
#pragma unroll
            for (int rr = 0; rr < 4; ++rr) {
                const float inv = 1.f / rsb[row0 + i * 16 + rr];
#pragma unroll
                for (int jj = 0; jj < 4; ++jj)
                    Ob[(row0 + i * 16 + rr) * D_DIM + col0 + jj * 16] = acc[i][jj][rr] * inv;
            }
    } else {
#pragma unroll
        for (int i = 0; i < 4; ++i)
#pragma unroll
            for (int rr = 0; rr < 4; ++rr) {
                const float inv = 1.f / rsb[row0 + i * 16 + rr];
#pragma unroll
                for (int jj = 0; jj < 4; ++jj)
                    atomicAdd(&Ob[(row0 + i * 16 + rr) * D_DIM + col0 + jj * 16],
                              acc[i][jj][rr] * inv);
            }
    }
}

// ---------------------------------------------------------------------------
// Workspace layout (MiB offsets), total ~119 MiB:
//   Q [0,16) K [16,32) V [32,48) Vt [48,64) Xh [64,80) Wt [80,86)
//   P [86,118)  row_sum [118, 118+32KiB)
// ---------------------------------------------------------------------------
extern "C" void kernel_launch(void* const* d_in, const int* in_sizes, int n_in,
                              void* d_out, int out_size, void* d_ws, size_t ws_size,
                              hipStream_t stream)
{
    const float* x  = (const float*)d_in[0];
    const float* Wq = (const float*)d_in[1];
    const float* Wk = (const float*)d_in[2];
    const float* Wv = (const float*)d_in[3];
    float* out = (float*)d_out;

    char* ws = (char*)d_ws;
    const long MiB = 1024 * 1024;
    _Float16* Q  = (_Float16*)(ws + 0 * MiB);
    _Float16* K  = (_Float16*)(ws + 16 * MiB);
    _Float16* V  = (_Float16*)(ws + 32 * MiB);
    _Float16* Vt = (_Float16*)(ws + 48 * MiB);
    _Float16* Xh = (_Float16*)(ws + 64 * MiB);
    _Float16* Wt = (_Float16*)(ws + 80 * MiB);
    _Float16* P  = (_Float16*)(ws + 86 * MiB);
    float*    RS = (float*)   (ws + 118 * MiB);

    init_kernel<<<dim3(8192 + 3072), dim3(256), 0, stream>>>(x, Xh, (float4*)out, RS,
                                                             Wq, Wk, Wv, Wt);
    proj_kernel<<<dim3(512), dim3(256), 0, stream>>>(Xh, Wt, Q, K, V);
    transpose_v_kernel<<<dim3(16, 32, 4), dim3(256), 0, stream>>>(V, Vt);
    scores_exp_kernel<<<dim3(544), dim3(256), 0, stream>>>(Q, K, P, RS);
    pv_kernel<<<dim3(768), dim3(256), 0, stream>>>(P, Vt, RS, out);
}

// Round 10
// 155.070 us; speedup vs baseline: 1.3169x; 1.3169x over previous
//
#include <hip/hip_runtime.h>

typedef _Float16 half8 __attribute__((ext_vector_type(8)));
typedef _Float16 half4 __attribute__((ext_vector_type(4)));
typedef float f32x4 __attribute__((ext_vector_type(4)));

#define ATT_SCALE 0.03125f   // 1/sqrt(1024)
#define S_LEN 2048
#define D_DIM 1024
#define NB 4

// async 16B HBM -> LDS copy (gfx950 global_load_lds_dwordx4).
// LDS dest must be wave-uniform base; HW adds lane*16.
__device__ __forceinline__ void async_cp16(const _Float16* g, _Float16* l)
{
    __builtin_amdgcn_global_load_lds(
        (const __attribute__((address_space(1))) void*)g,
        (__attribute__((address_space(3))) void*)l, 16, 0, 0);
}

// ---------------------------------------------------------------------------
// Shared GEMM core, BK=64 m97-structure (round-8 verified: 64.1 µs proj,
// 0 bank conflicts, multi-block overlap). 256 thr / 4 waves, 128x128 tile.
// T2 XOR-swizzle byte^=(row&7)<<4 on per-lane global SOURCE + ds_read addr.
// ---------------------------------------------------------------------------
__device__ __forceinline__ void gemm_core64(const _Float16* __restrict__ Ag,
                                            const _Float16* __restrict__ Bg,
                                            int lda, int ldb, int ksteps64,
                                            f32x4 acc[4][4])
{
    __shared__ _Float16 As[128 * 64];
    __shared__ _Float16 Bs[128 * 64];

    const int t    = threadIdx.x;
    const int wave = t >> 6;
    const int lane = t & 63;
    const int wm   = (wave >> 1) * 64;
    const int wn   = (wave & 1) * 64;
    const int lg   = lane >> 4;
    const int lr   = lane & 15;

    const int tr = t >> 3;
    const int tc = ((t & 7) ^ (tr & 7)) * 8;       // swizzled source col (halves)
    const int ldso = wave * 512;

    const _Float16* ap0 = Ag + (long)(0 * 32 + tr) * lda + tc;
    const _Float16* ap1 = Ag + (long)(1 * 32 + tr) * lda + tc;
    const _Float16* ap2 = Ag + (long)(2 * 32 + tr) * lda + tc;
    const _Float16* ap3 = Ag + (long)(3 * 32 + tr) * lda + tc;
    const _Float16* bp0 = Bg + (long)(0 * 32 + tr) * ldb + tc;
    const _Float16* bp1 = Bg + (long)(1 * 32 + tr) * ldb + tc;
    const _Float16* bp2 = Bg + (long)(2 * 32 + tr) * ldb + tc;
    const _Float16* bp3 = Bg + (long)(3 * 32 + tr) * ldb + tc;

    const int arow = wm + lr;
    const int brow = wn + lr;

    for (int ks = 0; ks < ksteps64; ++ks) {
        __syncthreads();
        async_cp16(ap0, As + 0 * 2048 + ldso);
        async_cp16(ap1, As + 1 * 2048 + ldso);
        async_cp16(ap2, As + 2 * 2048 + ldso);
        async_cp16(ap3, As + 3 * 2048 + ldso);
        async_cp16(bp0, Bs + 0 * 2048 + ldso);
        async_cp16(bp1, Bs + 1 * 2048 + ldso);
        async_cp16(bp2, Bs + 2 * 2048 + ldso);
        async_cp16(bp3, Bs + 3 * 2048 + ldso);
        __syncthreads();

        ap0 += 64; ap1 += 64; ap2 += 64; ap3 += 64;
        bp0 += 64; bp1 += 64; bp2 += 64; bp3 += 64;

#pragma unroll
        for (int kk = 0; kk < 2; ++kk) {
            half8 af[4], bf[4];
#pragma unroll
            for (int mf = 0; mf < 4; ++mf) {
                const int row = arow + mf * 16;
                const int hof = (kk * 32 + lg * 8) ^ ((row & 7) * 8);
                af[mf] = *(const half8*)&As[row * 64 + hof];
            }
#pragma unroll
            for (int nf = 0; nf < 4; ++nf) {
                const int row = brow + nf * 16;
                const int hof = (kk * 32 + lg * 8) ^ ((row & 7) * 8);
                bf[nf] = *(const half8*)&Bs[row * 64 + hof];
            }
#pragma unroll
            for (int mf = 0; mf < 4; ++mf)
#pragma unroll
                for (int nf = 0; nf < 4; ++nf)
                    acc[mf][nf] = __builtin_amdgcn_mfma_f32_16x16x32_f16(
                        af[mf], bf[nf], acc[mf][nf], 0, 0, 0);
        }
    }
}

// ---------------------------------------------------------------------------
// 0) fused init: cast x fp32->fp16 + zero row sums (blocks < 8192);
//    transpose+cast W (blocks >= 8192). NO out-zeroing (pv writes every
//    element exactly once with plain stores now).
// ---------------------------------------------------------------------------
__global__ void init_kernel(const float* __restrict__ X, _Float16* __restrict__ Xh,
                            float* __restrict__ rs,
                            const float* __restrict__ Wq, const float* __restrict__ Wk,
                            const float* __restrict__ Wv, _Float16* __restrict__ Wt)
{
    const int bid = blockIdx.x;
    const int t   = threadIdx.x;
    if (bid < 8192) {
        const int i = bid * 256 + t;                 // 0 .. 2097151
        float4 v = ((const float4*)X)[i];
        half4 h;
        h.x = (_Float16)v.x; h.y = (_Float16)v.y; h.z = (_Float16)v.z; h.w = (_Float16)v.w;
        ((half4*)Xh)[i] = h;
        if (i < NB * S_LEN) rs[i] = 0.f;
        return;
    }
    __shared__ float tile[32][33];
    const int bb = bid - 8192;
    const int w  = bb >> 10;
    const int rem = bb & 1023;
    const int n0 = (rem & 31) * 32, k0 = (rem >> 5) * 32;
    const float* Wsrc = (w == 0) ? Wq : (w == 1) ? Wk : Wv;
    _Float16* dst = Wt + (long)w * D_DIM * D_DIM;
    const int tx = t & 31, ty = t >> 5;
#pragma unroll
    for (int j = 0; j < 4; ++j)
        tile[ty + 8 * j][tx] = Wsrc[(long)(k0 + ty + 8 * j) * D_DIM + n0 + tx];
    __syncthreads();
#pragma unroll
    for (int j = 0; j < 4; ++j)
        dst[(long)(n0 + ty + 8 * j) * D_DIM + k0 + tx] = (_Float16)tile[tx][ty + 8 * j];
}

// ---------------------------------------------------------------------------
// 3) QKV projection — round-8 exact structure: 128x128 tiles, BK=64,
//    grid 1536, bijective XCD swizzle. 64.1 µs / 0 conflicts verified.
// ---------------------------------------------------------------------------
__global__ __launch_bounds__(256) void proj_kernel(const _Float16* __restrict__ Xh,
                                                   const _Float16* __restrict__ Wt,
                                                   _Float16* __restrict__ Q,
                                                   _Float16* __restrict__ K,
                                                   _Float16* __restrict__ V)
{
    const int flat = blockIdx.x;
    const int swz  = (flat & 7) * 192 + (flat >> 3);   // nwg=1536
    const int nt = swz & 7, mt = (swz >> 3) & 63, w = swz >> 9;

    f32x4 acc[4][4];
#pragma unroll
    for (int i = 0; i < 4; ++i)
#pragma unroll
        for (int j = 0; j < 4; ++j) acc[i][j] = (f32x4){0.f, 0.f, 0.f, 0.f};

    const _Float16* Ag = Xh + (long)mt * 128 * D_DIM;
    const _Float16* Bg = Wt + (long)w * D_DIM * D_DIM + (long)nt * 128 * D_DIM;
    gemm_core64(Ag, Bg, D_DIM, D_DIM, D_DIM / 64, acc);

    _Float16* C = (w == 0) ? Q : (w == 1) ? K : V;
    const int t = threadIdx.x, wave = t >> 6, lane = t & 63;
    const int wm = (wave >> 1) * 64, wn = (wave & 1) * 64;
    const int lg = lane >> 4, lr = lane & 15;
    const long row0 = (long)mt * 128 + wm + 4 * lg;
    const long col0 = (long)nt * 128 + wn + lr;
#pragma unroll
    for (int i = 0; i < 4; ++i)
#pragma unroll
        for (int j = 0; j < 4; ++j)
#pragma unroll
            for (int r = 0; r < 4; ++r)
                C[(row0 + i * 16 + r) * D_DIM + col0 + j * 16] = (_Float16)acc[i][j][r];
}

// ---------------------------------------------------------------------------
// 5) merged scores_tv: blocks 0..543 = fused scores+exp (triangular grid,
//    XCD-balanced, round-8 structure); blocks 544..2591 = V transpose
//    [b][s][d] -> Vt [b][d][s]. Transpose blocks fill CUs left idle by the
//    scores triangle. Both results consumed by pv.
// ---------------------------------------------------------------------------
__global__ __launch_bounds__(256) void scores_tv_kernel(const _Float16* __restrict__ Q,
                                                        const _Float16* __restrict__ K,
                                                        const _Float16* __restrict__ V,
                                                        _Float16* __restrict__ P,
                                                        float* __restrict__ row_sum,
                                                        _Float16* __restrict__ Vt)
{
    __shared__ _Float16 ttile[64][72];
    if (blockIdx.x >= 544) {
        // ---- V transpose ----
        const int tv = blockIdx.x - 544;            // 0..2047
        const int d0 = (tv & 15) * 64;
        const int s0 = ((tv >> 4) & 31) * 64;
        const long b = tv >> 9;
        const _Float16* Vb = V + b * S_LEN * D_DIM;
        _Float16* Vtb = Vt + b * D_DIM * S_LEN;
        const int t = threadIdx.x;
        const int sr = t >> 3, c8 = (t & 7) * 8;

        *(half8*)&ttile[sr][c8]      = *(const half8*)&Vb[(long)(s0 + sr) * D_DIM + d0 + c8];
        *(half8*)&ttile[sr + 32][c8] = *(const half8*)&Vb[(long)(s0 + sr + 32) * D_DIM + d0 + c8];
        __syncthreads();

        const int dr = t >> 3, s8 = (t & 7) * 8;
        half8 o0, o1;
#pragma unroll
        for (int e = 0; e < 8; ++e) {
            o0[e] = ttile[s8 + e][dr];
            o1[e] = ttile[s8 + e][dr + 32];
        }
        *(half8*)&Vtb[(long)(d0 + dr) * S_LEN + s0 + s8]      = o0;
        *(half8*)&Vtb[(long)(d0 + dr + 32) * S_LEN + s0 + s8] = o1;
        return;
    }

    // ---- scores + exp ----
    const int xcd = blockIdx.x & 7;
    const int idx = blockIdx.x >> 3;      // 0..67
    const int b   = idx / 17;
    const int l   = idx % 17;
    int qt, kt;
    if (l <= xcd) { qt = xcd;      kt = l; }
    else          { qt = 15 - xcd; kt = l - xcd - 1; }

    f32x4 acc[4][4];
#pragma unroll
    for (int i = 0; i < 4; ++i)
#pragma unroll
        for (int j = 0; j < 4; ++j) acc[i][j] = (f32x4){0.f, 0.f, 0.f, 0.f};

    const _Float16* Ag = Q + ((long)b * S_LEN + qt * 128) * D_DIM;
    const _Float16* Bg = K + ((long)b * S_LEN + kt * 128) * D_DIM;
    gemm_core64(Ag, Bg, D_DIM, D_DIM, D_DIM / 64, acc);

    _Float16* Pb = P + (long)b * S_LEN * S_LEN;
    float* rsb = row_sum + (long)b * S_LEN;
    const int t = threadIdx.x, wave = t >> 6, lane = t & 63;
    const int wm = (wave >> 1) * 64, wn = (wave & 1) * 64;
    const int lg = lane >> 4, lr = lane & 15;
    const int row0 = qt * 128 + wm + 4 * lg;
    const int col0 = kt * 128 + wn + lr;

#pragma unroll
    for (int i = 0; i < 4; ++i) {
#pragma unroll
        for (int r = 0; r < 4; ++r) {
            const int row = row0 + i * 16 + r;
            float s = 0.f;
#pragma unroll
            for (int j = 0; j < 4; ++j) {
                const int col = col0 + j * 16;
                float p = (col <= row) ? __expf(acc[i][r * 0 + j][r] * 0.f + acc[i][j][r] * ATT_SCALE) : 0.f;
                s += p;
                Pb[(long)row * S_LEN + col] = (_Float16)p;
            }
#pragma unroll
            for (int off = 1; off < 16; off <<= 1) s += __shfl_xor(s, off, 64);
            if (lr == 0) atomicAdd(&rsb[row], s);
        }
    }
}

// ---------------------------------------------------------------------------
// 6) O = (P @ V) / row_sum — NO split-K, NO atomics. 512 blocks, LPT order
//    (descending qt dispatches first; makespan ~34 BK64-steps/CU = split-K's).
//    idx%8 == (nt*4+b)%8 -> all 16 qt-blocks of one (nt,b) share an XCD ->
//    Vt slice L2-resident. Plain stores; every output written exactly once.
// ---------------------------------------------------------------------------
__global__ __launch_bounds__(256) void pv_kernel(const _Float16* __restrict__ P,
                                                 const _Float16* __restrict__ Vt,
                                                 const float* __restrict__ row_sum,
                                                 float* __restrict__ O)
{
    const int idx = blockIdx.x;           // 0..511
    const int qt  = 15 - (idx >> 5);      // descending qt = LPT
    const int rem = idx & 31;
    const int nt  = rem >> 2;             // 0..7
    const int b   = rem & 3;              // 0..3

    const int ks64 = (qt + 1) * 2;

    f32x4 acc[4][4];
#pragma unroll
    for (int i = 0; i < 4; ++i)
#pragma unroll
        for (int jj = 0; jj < 4; ++jj) acc[i][jj] = (f32x4){0.f, 0.f, 0.f, 0.f};

    const _Float16* Ag = P + ((long)b * S_LEN + qt * 128) * S_LEN;
    const _Float16* Bg = Vt + (long)b * D_DIM * S_LEN + (long)nt * 128 * S_LEN;
    gemm_core64(Ag, Bg, S_LEN, S_LEN, ks64, acc);

    float* Ob = O + (long)b * S_LEN * D_DIM;
    const float* rsb = row_sum + (long)b * S_LEN;
    const int t = threadIdx.x, wave = t >> 6, lane = t & 63;
    const int wm = (wave >> 1) * 64, wn = (wave & 1) * 64;
    const int lg = lane >> 4, lr = lane & 15;
    const long row0 = qt * 128 + wm + 4 * lg;
    const long col0 = (long)nt * 128 + wn + lr;

#pragma unroll
    for (int i = 0; i < 4; ++i)
#pragma unroll
        for (int rr = 0; rr < 4; ++rr) {
            const float inv = 1.f / rsb[row0 + i * 16 + rr];
#pragma unroll
            for (int jj = 0; jj < 4; ++jj)
                Ob[(row0 + i * 16 + rr) * D_DIM + col0 + jj * 16] = acc[i][jj][rr] * inv;
        }
}

// ---------------------------------------------------------------------------
// Workspace layout (MiB offsets), total ~119 MiB:
//   Q [0,16) K [16,32) V [32,48) Vt [48,64) Xh [64,80) Wt [80,86)
//   P [86,118)  row_sum [118, 118+32KiB)
// ---------------------------------------------------------------------------
extern "C" void kernel_launch(void* const* d_in, const int* in_sizes, int n_in,
                              void* d_out, int out_size, void* d_ws, size_t ws_size,
                              hipStream_t stream)
{
    const float* x  = (const float*)d_in[0];
    const float* Wq = (const float*)d_in[1];
    const float* Wk = (const float*)d_in[2];
    const float* Wv = (const float*)d_in[3];
    float* out = (float*)d_out;

    char* ws = (char*)d_ws;
    const long MiB = 1024 * 1024;
    _Float16* Q  = (_Float16*)(ws + 0 * MiB);
    _Float16* K  = (_Float16*)(ws + 16 * MiB);
    _Float16* V  = (_Float16*)(ws + 32 * MiB);
    _Float16* Vt = (_Float16*)(ws + 48 * MiB);
    _Float16* Xh = (_Float16*)(ws + 64 * MiB);
    _Float16* Wt = (_Float16*)(ws + 80 * MiB);
    _Float16* P  = (_Float16*)(ws + 86 * MiB);
    float*    RS = (float*)   (ws + 118 * MiB);

    init_kernel<<<dim3(8192 + 3072), dim3(256), 0, stream>>>(x, Xh, RS, Wq, Wk, Wv, Wt);
    proj_kernel<<<dim3(1536), dim3(256), 0, stream>>>(Xh, Wt, Q, K, V);
    scores_tv_kernel<<<dim3(2592), dim3(256), 0, stream>>>(Q, K, V, P, RS, Vt);
    pv_kernel<<<dim3(512), dim3(256), 0, stream>>>(P, Vt, RS, out);
}